// Round 1
// baseline (545.280 us; speedup 1.0000x reference)
//
#include <hip/hip_runtime.h>

// BatchTopK: relu(x), keep global top (k*1024) of 1024*24576 fp32, zero rest.
// Exact radix-select on positive-fp32 bit patterns + index-ordered tie-break
// (matches jax.lax.top_k's lower-index-first tie preference).

#define N_ELEM   25165824            // 1024 * 24576
#define NV       (N_ELEM / 4)        // float4 count (divisible)
#define HIST_SIZE 4096               // top-12-bit buckets
#define CAND_CAP  262144             // candidate pairs cap (~50K expected)
#define TIE_CAP   4096

// ws layout (uint32 units):
// [0 .. 4095]   hist
// [4096]        candidate count (atomic)
// [4097]        b12 (cutoff top-12-bit bucket)
// [4098]        c_above (count strictly above bucket b12)
// [4099..4103]  pad (8B-align candidates)
// [4104 .. ]    candidates: uint2 { bits, flat_idx }

__global__ void k_zero(unsigned* ws) {
    int i = blockIdx.x * blockDim.x + threadIdx.x;
    if (i < HIST_SIZE + 8) ws[i] = 0u;
}

__global__ void k_hist(const float4* __restrict__ x, unsigned* __restrict__ hist) {
    __shared__ unsigned lh[HIST_SIZE];
    for (int i = threadIdx.x; i < HIST_SIZE; i += blockDim.x) lh[i] = 0u;
    __syncthreads();
    int stride = gridDim.x * blockDim.x;
    for (int i = blockIdx.x * blockDim.x + threadIdx.x; i < NV; i += stride) {
        float4 v = x[i];
        if (v.x > 0.0f) atomicAdd(&lh[__float_as_uint(v.x) >> 20], 1u);
        if (v.y > 0.0f) atomicAdd(&lh[__float_as_uint(v.y) >> 20], 1u);
        if (v.z > 0.0f) atomicAdd(&lh[__float_as_uint(v.z) >> 20], 1u);
        if (v.w > 0.0f) atomicAdd(&lh[__float_as_uint(v.w) >> 20], 1u);
    }
    __syncthreads();
    for (int i = threadIdx.x; i < HIST_SIZE; i += blockDim.x)
        if (lh[i]) atomicAdd(&hist[i], lh[i]);
}

// Single block, 1024 threads: suffix-scan hist, find bucket containing the
// n_keep-th largest. meta[1] = b12, meta[2] = count strictly above b12.
__global__ void k_scan(const unsigned* __restrict__ hist, unsigned* __restrict__ meta,
                       const int* __restrict__ kptr) {
    __shared__ unsigned h[HIST_SIZE];
    __shared__ unsigned ps[1024];
    int t = threadIdx.x;
    unsigned nk = (unsigned)(*kptr) * 1024u;
    for (int i = t; i < HIST_SIZE; i += 1024) h[i] = hist[i];
    __syncthreads();
    unsigned p = h[t * 4] + h[t * 4 + 1] + h[t * 4 + 2] + h[t * 4 + 3];
    ps[t] = p;
    __syncthreads();
    for (int st = 1; st < 1024; st <<= 1) {
        unsigned v = (t + st < 1024) ? ps[t + st] : 0u;
        __syncthreads();
        ps[t] += v;
        __syncthreads();
    }
    unsigned S = (t < 1023) ? ps[t + 1] : 0u;   // suffix sum of chunks after mine
    for (int j = 3; j >= 0; --j) {
        int b = t * 4 + j;
        unsigned Sb = S + h[b];                  // S(b); S holds S(b+1)
        if (Sb >= nk && S < nk) { meta[1] = (unsigned)b; meta[2] = S; }
        S = Sb;
    }
}

__device__ __forceinline__ float proc_elem(float a, unsigned lo, unsigned hi, unsigned idx,
                                           unsigned* cnt, uint2* cand, unsigned cap) {
    float r = a > 0.0f ? a : 0.0f;
    unsigned bits = __float_as_uint(r);
    if (bits < lo) return 0.0f;
    if (bits < hi) {
        unsigned p = atomicAdd(cnt, 1u);
        if (p < cap) cand[p] = make_uint2(bits, idx);
    }
    return r;
}

// Provisional output (keep everything in/above cutoff bucket) + compact cutoff
// bucket candidates.
__global__ void k_out(const float4* __restrict__ x, float4* __restrict__ out,
                      unsigned* __restrict__ meta, uint2* __restrict__ cand, unsigned cap) {
    unsigned b12 = meta[1];
    unsigned lo = b12 << 20;
    unsigned hi = (b12 + 1u) << 20;
    unsigned* cnt = &meta[0];
    int stride = gridDim.x * blockDim.x;
    for (int i = blockIdx.x * blockDim.x + threadIdx.x; i < NV; i += stride) {
        float4 v = x[i];
        float4 o;
        unsigned base = (unsigned)i * 4u;
        o.x = proc_elem(v.x, lo, hi, base + 0u, cnt, cand, cap);
        o.y = proc_elem(v.y, lo, hi, base + 1u, cnt, cand, cap);
        o.z = proc_elem(v.z, lo, hi, base + 2u, cnt, cand, cap);
        o.w = proc_elem(v.w, lo, hi, base + 3u, cnt, cand, cap);
        out[i] = o;
    }
}

// Single block: refine radix levels 2 (bits[19:8]) and 3 (bits[7:0]) over the
// candidates, then fix up the provisional output (zero below-threshold, keep
// the r lowest-index ties).
__global__ void k_select(const unsigned* __restrict__ meta, const uint2* __restrict__ cand,
                         float* __restrict__ out, const int* __restrict__ kptr, unsigned cap) {
    __shared__ unsigned h2[4096];
    __shared__ unsigned ps[1024];
    __shared__ unsigned h3[256];
    __shared__ int ties[TIE_CAP];
    __shared__ unsigned tie_cnt;
    __shared__ unsigned s2_sh, ca2_sh, t3_sh, ca3_sh;
    int t = threadIdx.x;
    unsigned nk = (unsigned)(*kptr) * 1024u;
    unsigned ncand = meta[0]; if (ncand > cap) ncand = cap;
    unsigned b12 = meta[1];
    unsigned c_above = meta[2];
    unsigned m = nk - c_above;                    // rank to find within bucket, >=1
    for (int i = t; i < 4096; i += 1024) h2[i] = 0u;
    if (t < 256) h3[t] = 0u;
    if (t == 0) tie_cnt = 0u;
    __syncthreads();
    // level 2 histogram: bits[19:8]
    for (unsigned i = t; i < ncand; i += 1024)
        atomicAdd(&h2[(cand[i].x >> 8) & 0xFFFu], 1u);
    __syncthreads();
    unsigned p = h2[t * 4] + h2[t * 4 + 1] + h2[t * 4 + 2] + h2[t * 4 + 3];
    ps[t] = p;
    __syncthreads();
    for (int st = 1; st < 1024; st <<= 1) {
        unsigned v = (t + st < 1024) ? ps[t + st] : 0u;
        __syncthreads();
        ps[t] += v;
        __syncthreads();
    }
    {
        unsigned S = (t < 1023) ? ps[t + 1] : 0u;
        for (int j = 3; j >= 0; --j) {
            int b = t * 4 + j;
            unsigned Sb = S + h2[b];
            if (Sb >= m && S < m) { s2_sh = (unsigned)b; ca2_sh = S; }
            S = Sb;
        }
    }
    __syncthreads();
    unsigned s2 = s2_sh;
    unsigned m2 = m - ca2_sh;                     // rank within sub-bucket, >=1
    // level 3 histogram: bits[7:0] among sub-bucket s2
    for (unsigned i = t; i < ncand; i += 1024) {
        uint2 c = cand[i];
        if (((c.x >> 8) & 0xFFFu) == s2) atomicAdd(&h3[c.x & 0xFFu], 1u);
    }
    __syncthreads();
    if (t < 256) ps[t] = h3[t];
    __syncthreads();
    for (int st = 1; st < 256; st <<= 1) {
        unsigned v = 0u;
        if (t < 256) v = (t + st < 256) ? ps[t + st] : 0u;
        __syncthreads();
        if (t < 256) ps[t] += v;
        __syncthreads();
    }
    if (t < 256) {
        unsigned S3 = (t < 255) ? ps[t + 1] : 0u;
        unsigned Sb = S3 + h3[t];
        if (Sb >= m2 && S3 < m2) { t3_sh = (unsigned)t; ca3_sh = S3; }
    }
    __syncthreads();
    unsigned tau = (b12 << 20) | (s2 << 8) | t3_sh;
    unsigned r = m2 - ca3_sh;                     // number of ties (== tau) to keep
    // fixup: zero below tau, collect exact ties
    for (unsigned i = t; i < ncand; i += 1024) {
        uint2 c = cand[i];
        if (c.x < tau) {
            out[c.y] = 0.0f;
        } else if (c.x == tau) {
            unsigned q = atomicAdd(&tie_cnt, 1u);
            if (q < TIE_CAP) ties[q] = (int)c.y;
        }
    }
    __syncthreads();
    unsigned tc = tie_cnt; if (tc > TIE_CAP) tc = TIE_CAP;
    // keep the r lowest-index ties (jax top_k tie-break), zero the others
    for (unsigned e = t; e < tc; e += 1024) {
        int my = ties[e];
        unsigned rank = 0u;
        for (unsigned j = 0; j < tc; ++j) rank += (ties[j] < my) ? 1u : 0u;
        if (rank >= r) out[my] = 0.0f;
    }
}

extern "C" void kernel_launch(void* const* d_in, const int* in_sizes, int n_in,
                              void* d_out, int out_size, void* d_ws, size_t ws_size,
                              hipStream_t stream) {
    const float* x = (const float*)d_in[0];
    const int* kptr = (const int*)d_in[1];
    float* out = (float*)d_out;
    unsigned* ws32 = (unsigned*)d_ws;
    unsigned* hist = ws32;
    unsigned* meta = ws32 + HIST_SIZE;
    uint2* cand = (uint2*)(ws32 + HIST_SIZE + 8);

    unsigned cap = CAND_CAP;
    size_t hdr = (size_t)(HIST_SIZE + 8) * sizeof(unsigned);
    if (ws_size < hdr + (size_t)CAND_CAP * sizeof(uint2)) {
        cap = (ws_size > hdr) ? (unsigned)((ws_size - hdr) / sizeof(uint2)) : 0u;
    }

    k_zero<<<(HIST_SIZE + 8 + 255) / 256, 256, 0, stream>>>(ws32);
    k_hist<<<2048, 256, 0, stream>>>((const float4*)x, hist);
    k_scan<<<1, 1024, 0, stream>>>(hist, meta, kptr);
    k_out<<<2048, 256, 0, stream>>>((const float4*)x, (float4*)out, meta, cand, cap);
    k_select<<<1, 1024, 0, stream>>>(meta, cand, out, kptr, cap);
}

// Round 2
// 141.533 us; speedup vs baseline: 3.8527x; 3.8527x over previous
//
#include <hip/hip_runtime.h>

// BatchTopK: relu(x), keep global top (k*1024) of 1024*24576 fp32, zero rest.
// Exact radix-select on positive-fp32 bit patterns + index-ordered tie-break
// (matches jax.lax.top_k's lower-index-first tie preference).
//
// R2: block-local LDS candidate aggregation in k_out (one global atomic per
// block instead of one per candidate) — R1 showed 45K serialized single-address
// global atomics cost 453us (10ns each).

#define N_ELEM   25165824            // 1024 * 24576
#define NV       (N_ELEM / 4)        // float4 count (divisible)
#define HIST_SIZE 4096               // top-12-bit buckets
#define CAND_CAP  262144             // candidate pairs cap (~45K expected)
#define TIE_CAP   4096
#define LCAP     512                 // per-block LDS candidate buffer

// ws layout (uint32 units):
// [0 .. 4095]   hist
// [4096]        candidate count (atomic)
// [4097]        b12 (cutoff top-12-bit bucket)
// [4098]        c_above (count strictly above bucket b12)
// [4099..4103]  pad (8B-align candidates)
// [4104 .. ]    candidates: uint2 { bits, flat_idx }

__global__ void k_zero(unsigned* ws) {
    int i = blockIdx.x * blockDim.x + threadIdx.x;
    if (i < HIST_SIZE + 8) ws[i] = 0u;
}

__global__ void k_hist(const float4* __restrict__ x, unsigned* __restrict__ hist) {
    __shared__ unsigned lh[HIST_SIZE];
    for (int i = threadIdx.x; i < HIST_SIZE; i += blockDim.x) lh[i] = 0u;
    __syncthreads();
    int stride = gridDim.x * blockDim.x;
    for (int i = blockIdx.x * blockDim.x + threadIdx.x; i < NV; i += stride) {
        float4 v = x[i];
        if (v.x > 0.0f) atomicAdd(&lh[__float_as_uint(v.x) >> 20], 1u);
        if (v.y > 0.0f) atomicAdd(&lh[__float_as_uint(v.y) >> 20], 1u);
        if (v.z > 0.0f) atomicAdd(&lh[__float_as_uint(v.z) >> 20], 1u);
        if (v.w > 0.0f) atomicAdd(&lh[__float_as_uint(v.w) >> 20], 1u);
    }
    __syncthreads();
    for (int i = threadIdx.x; i < HIST_SIZE; i += blockDim.x)
        if (lh[i]) atomicAdd(&hist[i], lh[i]);
}

// Single block, 1024 threads: suffix-scan hist, find bucket containing the
// n_keep-th largest. meta[1] = b12, meta[2] = count strictly above b12.
__global__ void k_scan(const unsigned* __restrict__ hist, unsigned* __restrict__ meta,
                       const int* __restrict__ kptr) {
    __shared__ unsigned h[HIST_SIZE];
    __shared__ unsigned ps[1024];
    int t = threadIdx.x;
    unsigned nk = (unsigned)(*kptr) * 1024u;
    for (int i = t; i < HIST_SIZE; i += 1024) h[i] = hist[i];
    __syncthreads();
    unsigned p = h[t * 4] + h[t * 4 + 1] + h[t * 4 + 2] + h[t * 4 + 3];
    ps[t] = p;
    __syncthreads();
    for (int st = 1; st < 1024; st <<= 1) {
        unsigned v = (t + st < 1024) ? ps[t + st] : 0u;
        __syncthreads();
        ps[t] += v;
        __syncthreads();
    }
    unsigned S = (t < 1023) ? ps[t + 1] : 0u;   // suffix sum of chunks after mine
    for (int j = 3; j >= 0; --j) {
        int b = t * 4 + j;
        unsigned Sb = S + h[b];                  // S(b); S holds S(b+1)
        if (Sb >= nk && S < nk) { meta[1] = (unsigned)b; meta[2] = S; }
        S = Sb;
    }
}

// Provisional output (keep everything in/above cutoff bucket) + compact cutoff
// bucket candidates via block-local LDS buffer (1 global atomic per block).
__global__ void k_out(const float4* __restrict__ x, float4* __restrict__ out,
                      unsigned* __restrict__ meta, uint2* __restrict__ cand, unsigned cap) {
    __shared__ uint2 lcand[LCAP];
    __shared__ unsigned lcnt;
    __shared__ unsigned gbase;
    if (threadIdx.x == 0) lcnt = 0u;
    __syncthreads();
    unsigned b12 = meta[1];
    unsigned lo = b12 << 20;
    unsigned hi = (b12 + 1u) << 20;
    unsigned* gcnt = &meta[0];
    int stride = gridDim.x * blockDim.x;
    for (int i = blockIdx.x * blockDim.x + threadIdx.x; i < NV; i += stride) {
        float4 v = x[i];
        float4 o;
        unsigned base = (unsigned)i * 4u;
        #pragma unroll
        for (int c = 0; c < 4; ++c) {
            float a = (c == 0) ? v.x : (c == 1) ? v.y : (c == 2) ? v.z : v.w;
            float r = a > 0.0f ? a : 0.0f;
            unsigned bits = __float_as_uint(r);
            float oo = r;
            if (bits < lo) oo = 0.0f;
            else if (bits < hi) {
                unsigned p = atomicAdd(&lcnt, 1u);           // LDS atomic
                if (p < LCAP) lcand[p] = make_uint2(bits, base + (unsigned)c);
                else {                                        // spill (≈never)
                    unsigned q = atomicAdd(gcnt, 1u);
                    if (q < cap) cand[q] = make_uint2(bits, base + (unsigned)c);
                }
            }
            if (c == 0) o.x = oo; else if (c == 1) o.y = oo;
            else if (c == 2) o.z = oo; else o.w = oo;
        }
        out[i] = o;
    }
    __syncthreads();
    unsigned n = lcnt < LCAP ? lcnt : LCAP;
    if (threadIdx.x == 0 && n) gbase = atomicAdd(gcnt, n);   // 1 global atomic/block
    __syncthreads();
    for (unsigned e = threadIdx.x; e < n; e += blockDim.x) {
        unsigned q = gbase + e;
        if (q < cap) cand[q] = lcand[e];
    }
}

// Single block: refine radix levels 2 (bits[19:8]) and 3 (bits[7:0]) over the
// candidates, then fix up the provisional output (zero below-threshold, keep
// the r lowest-index ties).
__global__ void k_select(const unsigned* __restrict__ meta, const uint2* __restrict__ cand,
                         float* __restrict__ out, const int* __restrict__ kptr, unsigned cap) {
    __shared__ unsigned h2[4096];
    __shared__ unsigned ps[1024];
    __shared__ unsigned h3[256];
    __shared__ int ties[TIE_CAP];
    __shared__ unsigned tie_cnt;
    __shared__ unsigned s2_sh, ca2_sh, t3_sh, ca3_sh;
    int t = threadIdx.x;
    unsigned nk = (unsigned)(*kptr) * 1024u;
    unsigned ncand = meta[0]; if (ncand > cap) ncand = cap;
    unsigned b12 = meta[1];
    unsigned c_above = meta[2];
    unsigned m = nk - c_above;                    // rank to find within bucket, >=1
    for (int i = t; i < 4096; i += 1024) h2[i] = 0u;
    if (t < 256) h3[t] = 0u;
    if (t == 0) tie_cnt = 0u;
    __syncthreads();
    // level 2 histogram: bits[19:8]
    for (unsigned i = t; i < ncand; i += 1024)
        atomicAdd(&h2[(cand[i].x >> 8) & 0xFFFu], 1u);
    __syncthreads();
    unsigned p = h2[t * 4] + h2[t * 4 + 1] + h2[t * 4 + 2] + h2[t * 4 + 3];
    ps[t] = p;
    __syncthreads();
    for (int st = 1; st < 1024; st <<= 1) {
        unsigned v = (t + st < 1024) ? ps[t + st] : 0u;
        __syncthreads();
        ps[t] += v;
        __syncthreads();
    }
    {
        unsigned S = (t < 1023) ? ps[t + 1] : 0u;
        for (int j = 3; j >= 0; --j) {
            int b = t * 4 + j;
            unsigned Sb = S + h2[b];
            if (Sb >= m && S < m) { s2_sh = (unsigned)b; ca2_sh = S; }
            S = Sb;
        }
    }
    __syncthreads();
    unsigned s2 = s2_sh;
    unsigned m2 = m - ca2_sh;                     // rank within sub-bucket, >=1
    // level 3 histogram: bits[7:0] among sub-bucket s2
    for (unsigned i = t; i < ncand; i += 1024) {
        uint2 c = cand[i];
        if (((c.x >> 8) & 0xFFFu) == s2) atomicAdd(&h3[c.x & 0xFFu], 1u);
    }
    __syncthreads();
    if (t < 256) ps[t] = h3[t];
    __syncthreads();
    for (int st = 1; st < 256; st <<= 1) {
        unsigned v = 0u;
        if (t < 256) v = (t + st < 256) ? ps[t + st] : 0u;
        __syncthreads();
        if (t < 256) ps[t] += v;
        __syncthreads();
    }
    if (t < 256) {
        unsigned S3 = (t < 255) ? ps[t + 1] : 0u;
        unsigned Sb = S3 + h3[t];
        if (Sb >= m2 && S3 < m2) { t3_sh = (unsigned)t; ca3_sh = S3; }
    }
    __syncthreads();
    unsigned tau = (b12 << 20) | (s2 << 8) | t3_sh;
    unsigned r = m2 - ca3_sh;                     // number of ties (== tau) to keep
    // fixup: zero below tau, collect exact ties
    for (unsigned i = t; i < ncand; i += 1024) {
        uint2 c = cand[i];
        if (c.x < tau) {
            out[c.y] = 0.0f;
        } else if (c.x == tau) {
            unsigned q = atomicAdd(&tie_cnt, 1u);
            if (q < TIE_CAP) ties[q] = (int)c.y;
        }
    }
    __syncthreads();
    unsigned tc = tie_cnt; if (tc > TIE_CAP) tc = TIE_CAP;
    // keep the r lowest-index ties (jax top_k tie-break), zero the others
    for (unsigned e = t; e < tc; e += 1024) {
        int my = ties[e];
        unsigned rank = 0u;
        for (unsigned j = 0; j < tc; ++j) rank += (ties[j] < my) ? 1u : 0u;
        if (rank >= r) out[my] = 0.0f;
    }
}

extern "C" void kernel_launch(void* const* d_in, const int* in_sizes, int n_in,
                              void* d_out, int out_size, void* d_ws, size_t ws_size,
                              hipStream_t stream) {
    const float* x = (const float*)d_in[0];
    const int* kptr = (const int*)d_in[1];
    float* out = (float*)d_out;
    unsigned* ws32 = (unsigned*)d_ws;
    unsigned* hist = ws32;
    unsigned* meta = ws32 + HIST_SIZE;
    uint2* cand = (uint2*)(ws32 + HIST_SIZE + 8);

    unsigned cap = CAND_CAP;
    size_t hdr = (size_t)(HIST_SIZE + 8) * sizeof(unsigned);
    if (ws_size < hdr + (size_t)CAND_CAP * sizeof(uint2)) {
        cap = (ws_size > hdr) ? (unsigned)((ws_size - hdr) / sizeof(uint2)) : 0u;
    }

    k_zero<<<(HIST_SIZE + 8 + 255) / 256, 256, 0, stream>>>(ws32);
    k_hist<<<2048, 256, 0, stream>>>((const float4*)x, hist);
    k_scan<<<1, 1024, 0, stream>>>(hist, meta, kptr);
    k_out<<<2048, 256, 0, stream>>>((const float4*)x, (float4*)out, meta, cand, cap);
    k_select<<<1, 1024, 0, stream>>>(meta, cand, out, kptr, cap);
}

// Round 3
// 128.463 us; speedup vs baseline: 4.2446x; 1.1017x over previous
//
#include <hip/hip_runtime.h>

// BatchTopK: relu(x), keep global top (k*1024) of 1024*24576 fp32, zero rest.
// Exact radix-select on positive-fp32 bit patterns + index-ordered tie-break.
//
// R3: sampled conservative floor F so the exact histogram only counts the
// ~2% of elements that can matter (kills LDS-atomic serialization seen in R2:
// 1.2M bank-conflict cycles, 67us for a 15us read). 8-way replicated global
// histogram cuts flush atomic contention. Always-enqueued guarded fallback
// keeps exactness for any input.

#define N_ELEM   25165824            // 1024 * 24576
#define NV       (N_ELEM / 4)        // float4 count (divisible)
#define HIST_SIZE 4096               // top-12-bit buckets
#define HREP     8                   // histogram replicas
#define CAND_CAP  262144
#define TIE_CAP   4096
#define LCAP     512                 // per-block LDS candidate buffer

// ws layout (uint32 units):
// [0 .. 32767]     hist replicas (8 x 4096), exact counts of bits >= F
// [32768 .. 36863] hist_s (sampled histogram)
// [36864 .. 36871] meta: [0]=cand cnt [1]=b12 [2]=c_above [3]=fail
//                        [4]=F_bits   [5]=keepall [6,7] pad
// [36872 .. ]      candidates: uint2 { bits, flat_idx }
#define META_OFF 36864
#define CAND_OFF 36872
#define ZERO_WORDS (CAND_OFF)

__global__ void k_zero(unsigned* ws) {
    int i = blockIdx.x * blockDim.x + threadIdx.x;
    if (i < ZERO_WORDS) ws[i] = 0u;
}

// 1/16 coalesced sample histogram (wave reads 64 consecutive float4s, skips 960)
__global__ void k_sample(const float4* __restrict__ x, unsigned* __restrict__ hist_s) {
    __shared__ unsigned lh[HIST_SIZE];
    for (int i = threadIdx.x; i < HIST_SIZE; i += blockDim.x) lh[i] = 0u;
    __syncthreads();
    int gt = blockIdx.x * blockDim.x + threadIdx.x;
    for (int s = gt; s < NV / 16; s += 64 * 256) {
        int c = s >> 6, l = s & 63;
        float4 v = x[c * 1024 + l];
        float r;
        r = v.x > 0.0f ? v.x : 0.0f; if (r > 0.0f) atomicAdd(&lh[__float_as_uint(r) >> 20], 1u);
        r = v.y > 0.0f ? v.y : 0.0f; if (r > 0.0f) atomicAdd(&lh[__float_as_uint(r) >> 20], 1u);
        r = v.z > 0.0f ? v.z : 0.0f; if (r > 0.0f) atomicAdd(&lh[__float_as_uint(r) >> 20], 1u);
        r = v.w > 0.0f ? v.w : 0.0f; if (r > 0.0f) atomicAdd(&lh[__float_as_uint(r) >> 20], 1u);
    }
    __syncthreads();
    for (int i = threadIdx.x; i < HIST_SIZE; i += blockDim.x)
        if (lh[i]) atomicAdd(&hist_s[i], lh[i]);
}

// Pick floor: highest bucket whose sampled suffix count >= nk/2 (so exact
// count(>=F) ~ 8*nk). meta[4] = F bits (default 1 = all positives).
__global__ void k_pick(const unsigned* __restrict__ hist_s, unsigned* __restrict__ meta,
                       const int* __restrict__ kptr) {
    __shared__ unsigned h[HIST_SIZE];
    __shared__ unsigned ps[1024];
    int t = threadIdx.x;
    unsigned nk = (unsigned)(*kptr) * 1024u;
    unsigned thr = nk / 2u; if (thr < 1u) thr = 1u;
    if (t == 0) meta[4] = 1u;
    for (int i = t; i < HIST_SIZE; i += 1024) h[i] = hist_s[i];
    __syncthreads();
    unsigned p = h[t * 4] + h[t * 4 + 1] + h[t * 4 + 2] + h[t * 4 + 3];
    ps[t] = p;
    __syncthreads();
    for (int st = 1; st < 1024; st <<= 1) {
        unsigned v = (t + st < 1024) ? ps[t + st] : 0u;
        __syncthreads();
        ps[t] += v;
        __syncthreads();
    }
    unsigned S = (t < 1023) ? ps[t + 1] : 0u;
    for (int j = 3; j >= 0; --j) {
        int b = t * 4 + j;
        unsigned Sb = S + h[b];
        if (Sb >= thr && S < thr) meta[4] = ((unsigned)b) << 20;
        S = Sb;
    }
}

// Exact histogram of elements with bits >= F only (~2% of data).
__global__ void k_hist(const float4* __restrict__ x, unsigned* __restrict__ hist,
                       const unsigned* __restrict__ meta) {
    __shared__ unsigned lh[HIST_SIZE];
    for (int i = threadIdx.x; i < HIST_SIZE; i += blockDim.x) lh[i] = 0u;
    __syncthreads();
    unsigned F = meta[4];
    int stride = gridDim.x * blockDim.x;
    for (int i = blockIdx.x * blockDim.x + threadIdx.x; i < NV; i += stride) {
        float4 v = x[i];
        float r; unsigned b;
        r = v.x > 0.0f ? v.x : 0.0f; b = __float_as_uint(r); if (b >= F) atomicAdd(&lh[b >> 20], 1u);
        r = v.y > 0.0f ? v.y : 0.0f; b = __float_as_uint(r); if (b >= F) atomicAdd(&lh[b >> 20], 1u);
        r = v.z > 0.0f ? v.z : 0.0f; b = __float_as_uint(r); if (b >= F) atomicAdd(&lh[b >> 20], 1u);
        r = v.w > 0.0f ? v.w : 0.0f; b = __float_as_uint(r); if (b >= F) atomicAdd(&lh[b >> 20], 1u);
    }
    __syncthreads();
    unsigned* gh = hist + (blockIdx.x & (HREP - 1)) * HIST_SIZE;
    for (int i = threadIdx.x; i < HIST_SIZE; i += blockDim.x)
        if (lh[i]) atomicAdd(&gh[i], lh[i]);
}

// Fallback (guarded on meta[3]): add the complement (0 < bits < F) so the
// replica histograms become the FULL histogram. Runs only if floor failed.
__global__ void k_hist_fb(const float4* __restrict__ x, unsigned* __restrict__ hist,
                          const unsigned* __restrict__ meta) {
    if (meta[3] == 0u) return;
    __shared__ unsigned lh[HIST_SIZE];
    for (int i = threadIdx.x; i < HIST_SIZE; i += blockDim.x) lh[i] = 0u;
    __syncthreads();
    unsigned F = meta[4];
    int stride = gridDim.x * blockDim.x;
    for (int i = blockIdx.x * blockDim.x + threadIdx.x; i < NV; i += stride) {
        float4 v = x[i];
        float r; unsigned b;
        r = v.x > 0.0f ? v.x : 0.0f; b = __float_as_uint(r); if (b >= 1u && b < F) atomicAdd(&lh[b >> 20], 1u);
        r = v.y > 0.0f ? v.y : 0.0f; b = __float_as_uint(r); if (b >= 1u && b < F) atomicAdd(&lh[b >> 20], 1u);
        r = v.z > 0.0f ? v.z : 0.0f; b = __float_as_uint(r); if (b >= 1u && b < F) atomicAdd(&lh[b >> 20], 1u);
        r = v.w > 0.0f ? v.w : 0.0f; b = __float_as_uint(r); if (b >= 1u && b < F) atomicAdd(&lh[b >> 20], 1u);
    }
    __syncthreads();
    unsigned* gh = hist + (blockIdx.x & (HREP - 1)) * HIST_SIZE;
    for (int i = threadIdx.x; i < HIST_SIZE; i += blockDim.x)
        if (lh[i]) atomicAdd(&gh[i], lh[i]);
}

// Suffix-scan the (replica-summed) histogram; locate cutoff bucket.
// is_fb==0: if total < nk -> set fail flag (floor too high), else b12/c_above.
// is_fb==1: runs only if fail; if still total < nk -> keepall.
__global__ void k_scan(const unsigned* __restrict__ hist, unsigned* __restrict__ meta,
                       const int* __restrict__ kptr, int is_fb) {
    if (is_fb && meta[3] == 0u) return;
    __shared__ unsigned h[HIST_SIZE];
    __shared__ unsigned ps[1024];
    int t = threadIdx.x;
    unsigned nk = (unsigned)(*kptr) * 1024u;
    for (int i = t; i < HIST_SIZE; i += 1024) {
        unsigned s = 0u;
        #pragma unroll
        for (int r = 0; r < HREP; ++r) s += hist[r * HIST_SIZE + i];
        h[i] = s;
    }
    __syncthreads();
    unsigned p = h[t * 4] + h[t * 4 + 1] + h[t * 4 + 2] + h[t * 4 + 3];
    ps[t] = p;
    __syncthreads();
    for (int st = 1; st < 1024; st <<= 1) {
        unsigned v = (t + st < 1024) ? ps[t + st] : 0u;
        __syncthreads();
        ps[t] += v;
        __syncthreads();
    }
    unsigned total = ps[0];
    if (total < nk) {
        if (t == 0) {
            if (!is_fb) meta[3] = 1u;        // trigger fallback
            else        meta[5] = 1u;        // fewer positives than nk: keep all
        }
        return;
    }
    unsigned S = (t < 1023) ? ps[t + 1] : 0u;
    for (int j = 3; j >= 0; --j) {
        int b = t * 4 + j;
        unsigned Sb = S + h[b];
        if (Sb >= nk && S < nk) { meta[1] = (unsigned)b; meta[2] = S; }
        S = Sb;
    }
}

// Provisional output + cutoff-bucket candidate compaction (LDS-buffered).
__global__ void k_out(const float4* __restrict__ x, float4* __restrict__ out,
                      unsigned* __restrict__ meta, uint2* __restrict__ cand, unsigned cap) {
    __shared__ uint2 lcand[LCAP];
    __shared__ unsigned lcnt;
    __shared__ unsigned gbase;
    if (threadIdx.x == 0) lcnt = 0u;
    __syncthreads();
    unsigned keepall = meta[5];
    unsigned b12 = meta[1];
    unsigned lo = keepall ? 0u : (b12 << 20);
    unsigned hi = keepall ? 0u : ((b12 + 1u) << 20);
    unsigned* gcnt = &meta[0];
    int stride = gridDim.x * blockDim.x;
    for (int i = blockIdx.x * blockDim.x + threadIdx.x; i < NV; i += stride) {
        float4 v = x[i];
        float4 o;
        unsigned base = (unsigned)i * 4u;
        #pragma unroll
        for (int c = 0; c < 4; ++c) {
            float a = (c == 0) ? v.x : (c == 1) ? v.y : (c == 2) ? v.z : v.w;
            float r = a > 0.0f ? a : 0.0f;
            unsigned bits = __float_as_uint(r);
            float oo = r;
            if (bits < lo) oo = 0.0f;
            else if (bits < hi) {
                unsigned p = atomicAdd(&lcnt, 1u);           // LDS atomic
                if (p < LCAP) lcand[p] = make_uint2(bits, base + (unsigned)c);
                else {                                        // spill (~never)
                    unsigned q = atomicAdd(gcnt, 1u);
                    if (q < cap) cand[q] = make_uint2(bits, base + (unsigned)c);
                }
            }
            if (c == 0) o.x = oo; else if (c == 1) o.y = oo;
            else if (c == 2) o.z = oo; else o.w = oo;
        }
        out[i] = o;
    }
    __syncthreads();
    unsigned n = lcnt < LCAP ? lcnt : LCAP;
    if (threadIdx.x == 0 && n) gbase = atomicAdd(gcnt, n);   // 1 global atomic/block
    __syncthreads();
    for (unsigned e = threadIdx.x; e < n; e += blockDim.x) {
        unsigned q = gbase + e;
        if (q < cap) cand[q] = lcand[e];
    }
}

// Refine bits[19:8] then bits[7:0] over candidates; fix up output.
__global__ void k_select(const unsigned* __restrict__ meta, const uint2* __restrict__ cand,
                         float* __restrict__ out, const int* __restrict__ kptr, unsigned cap) {
    if (meta[5]) return;   // keep-all degenerate case
    __shared__ unsigned h2[4096];
    __shared__ unsigned ps[1024];
    __shared__ unsigned h3[256];
    __shared__ int ties[TIE_CAP];
    __shared__ unsigned tie_cnt;
    __shared__ unsigned s2_sh, ca2_sh, t3_sh, ca3_sh;
    int t = threadIdx.x;
    unsigned nk = (unsigned)(*kptr) * 1024u;
    unsigned ncand = meta[0]; if (ncand > cap) ncand = cap;
    unsigned b12 = meta[1];
    unsigned c_above = meta[2];
    unsigned m = nk - c_above;                    // rank within bucket, >=1
    for (int i = t; i < 4096; i += 1024) h2[i] = 0u;
    if (t < 256) h3[t] = 0u;
    if (t == 0) tie_cnt = 0u;
    __syncthreads();
    for (unsigned i = t; i < ncand; i += 1024)
        atomicAdd(&h2[(cand[i].x >> 8) & 0xFFFu], 1u);
    __syncthreads();
    unsigned p = h2[t * 4] + h2[t * 4 + 1] + h2[t * 4 + 2] + h2[t * 4 + 3];
    ps[t] = p;
    __syncthreads();
    for (int st = 1; st < 1024; st <<= 1) {
        unsigned v = (t + st < 1024) ? ps[t + st] : 0u;
        __syncthreads();
        ps[t] += v;
        __syncthreads();
    }
    {
        unsigned S = (t < 1023) ? ps[t + 1] : 0u;
        for (int j = 3; j >= 0; --j) {
            int b = t * 4 + j;
            unsigned Sb = S + h2[b];
            if (Sb >= m && S < m) { s2_sh = (unsigned)b; ca2_sh = S; }
            S = Sb;
        }
    }
    __syncthreads();
    unsigned s2 = s2_sh;
    unsigned m2 = m - ca2_sh;
    for (unsigned i = t; i < ncand; i += 1024) {
        uint2 c = cand[i];
        if (((c.x >> 8) & 0xFFFu) == s2) atomicAdd(&h3[c.x & 0xFFu], 1u);
    }
    __syncthreads();
    if (t < 256) ps[t] = h3[t];
    __syncthreads();
    for (int st = 1; st < 256; st <<= 1) {
        unsigned v = 0u;
        if (t < 256) v = (t + st < 256) ? ps[t + st] : 0u;
        __syncthreads();
        if (t < 256) ps[t] += v;
        __syncthreads();
    }
    if (t < 256) {
        unsigned S3 = (t < 255) ? ps[t + 1] : 0u;
        unsigned Sb = S3 + h3[t];
        if (Sb >= m2 && S3 < m2) { t3_sh = (unsigned)t; ca3_sh = S3; }
    }
    __syncthreads();
    unsigned tau = (b12 << 20) | (s2 << 8) | t3_sh;
    unsigned r = m2 - ca3_sh;                     // ties (== tau) to keep
    for (unsigned i = t; i < ncand; i += 1024) {
        uint2 c = cand[i];
        if (c.x < tau) {
            out[c.y] = 0.0f;
        } else if (c.x == tau) {
            unsigned q = atomicAdd(&tie_cnt, 1u);
            if (q < TIE_CAP) ties[q] = (int)c.y;
        }
    }
    __syncthreads();
    unsigned tc = tie_cnt; if (tc > TIE_CAP) tc = TIE_CAP;
    for (unsigned e = t; e < tc; e += 1024) {
        int my = ties[e];
        unsigned rank = 0u;
        for (unsigned j = 0; j < tc; ++j) rank += (ties[j] < my) ? 1u : 0u;
        if (rank >= r) out[my] = 0.0f;
    }
}

extern "C" void kernel_launch(void* const* d_in, const int* in_sizes, int n_in,
                              void* d_out, int out_size, void* d_ws, size_t ws_size,
                              hipStream_t stream) {
    const float* x = (const float*)d_in[0];
    const int* kptr = (const int*)d_in[1];
    float* out = (float*)d_out;
    unsigned* ws32 = (unsigned*)d_ws;
    unsigned* hist = ws32;                        // 8 replicas
    unsigned* hist_s = ws32 + HREP * HIST_SIZE;
    unsigned* meta = ws32 + META_OFF;
    uint2* cand = (uint2*)(ws32 + CAND_OFF);

    unsigned cap = CAND_CAP;
    size_t hdr = (size_t)CAND_OFF * sizeof(unsigned);
    if (ws_size < hdr + (size_t)CAND_CAP * sizeof(uint2)) {
        cap = (ws_size > hdr) ? (unsigned)((ws_size - hdr) / sizeof(uint2)) : 0u;
    }

    k_zero<<<(ZERO_WORDS + 255) / 256, 256, 0, stream>>>(ws32);
    k_sample<<<64, 256, 0, stream>>>((const float4*)x, hist_s);
    k_pick<<<1, 1024, 0, stream>>>(hist_s, meta, kptr);
    k_hist<<<2048, 256, 0, stream>>>((const float4*)x, hist, meta);
    k_scan<<<1, 1024, 0, stream>>>(hist, meta, kptr, 0);
    k_hist_fb<<<2048, 256, 0, stream>>>((const float4*)x, hist, meta);   // no-op unless fail
    k_scan<<<1, 1024, 0, stream>>>(hist, meta, kptr, 1);                 // no-op unless fail
    k_out<<<2048, 256, 0, stream>>>((const float4*)x, (float4*)out, meta, cand, cap);
    k_select<<<1, 1024, 0, stream>>>(meta, cand, out, kptr, cap);
}

// Round 4
// 115.310 us; speedup vs baseline: 4.7288x; 1.1141x over previous
//
#include <hip/hip_runtime.h>

// BatchTopK: relu(x), keep global top (k*1024) of 1024*24576 fp32, zero rest.
// Exact radix-select on positive-fp32 bit patterns + index-ordered tie-break.
//
// R4: single x pass. k_main reads x once, writes out=0 dense, histograms
// (floored at sampled F) and compacts ALL candidates >=F (~524K) to ws.
// Selection runs on the compact list; keepers scattered sparsely at the end.
// Removes the second 96MB x read of R3's k_out. Guarded exact fallback.

#define N_ELEM   25165824            // 1024 * 24576
#define NV       (N_ELEM / 4)        // float4 count
#define HIST_SIZE 4096               // top-12-bit buckets
#define HREP     8                   // main/level-2 histogram replicas
#define SREP     16                  // sample blocks / private replicas
#define NS       (NV / 64)           // sampled float4 count (1/64)
#define LCAP     1024                // per-block LDS candidate buffer
#define LCAP2    1024
#define TIE_CAP  4096
#define CAND2_CAP 262144
#define CAND_CAP  16777216

// ws layout (uint32 words):
#define H_OFF     0                  // 8 x 4096 main hist (counts bits >= F)
#define H2_OFF    32768              // 8 x 4096 level-2 hist (bits[19:8], bucket b12)
#define HS_OFF    65536              // 16 x 4096 private sample hists (no zero needed)
#define META_OFF  131072             // 8 words, see M_* below
#define CAND2_OFF 131080             // cutoff-bucket candidates, uint2
#define CAND_OFF  655368             // all candidates >= F, uint2 {bits, idx}
// meta: [0]=cand cnt [1]=b12 [2]=c_above [3]=fail [4]=F [5]=keepall [6]=tau [7]=cand2 cnt

// K1 (16 blocks): zero hist+h2+meta; 1/64 sample -> private hist_s replica.
__global__ void k_sample(const float4* __restrict__ x, unsigned* __restrict__ ws) {
    __shared__ unsigned lh[HIST_SIZE];
    for (int i = threadIdx.x; i < HIST_SIZE; i += blockDim.x) lh[i] = 0u;
    int gid = blockIdx.x * blockDim.x + threadIdx.x;
    for (int i = gid; i < HS_OFF; i += SREP * 256) ws[i] = 0u;   // zero hist + h2
    if (gid < 8) ws[META_OFF + gid] = 0u;
    __syncthreads();
    for (int s = gid; s < NS; s += SREP * 256) {
        int c = s >> 6, l = s & 63;                 // first 64 f4 of each 4096-f4 chunk
        float4 v = x[c * 4096 + l];
        if (v.x > 0.0f) atomicAdd(&lh[__float_as_uint(v.x) >> 20], 1u);
        if (v.y > 0.0f) atomicAdd(&lh[__float_as_uint(v.y) >> 20], 1u);
        if (v.z > 0.0f) atomicAdd(&lh[__float_as_uint(v.z) >> 20], 1u);
        if (v.w > 0.0f) atomicAdd(&lh[__float_as_uint(v.w) >> 20], 1u);
    }
    __syncthreads();
    unsigned* hs = ws + HS_OFF + blockIdx.x * HIST_SIZE;
    for (int i = threadIdx.x; i < HIST_SIZE; i += blockDim.x) hs[i] = lh[i];
}

// K2 (1 block): F = highest bucket with sampled suffix >= nk/8 (full ~ 8*nk).
__global__ void k_pick(unsigned* __restrict__ ws, const int* __restrict__ kptr) {
    __shared__ unsigned h[HIST_SIZE];
    __shared__ unsigned ps[1024];
    __shared__ unsigned F_sh;
    int t = threadIdx.x;
    if (t == 0) F_sh = 1u;
    unsigned nk = (unsigned)(*kptr) * 1024u;
    unsigned thr = nk / 8u; if (thr < 1u) thr = 1u;
    for (int i = t; i < HIST_SIZE; i += 1024) {
        unsigned s = 0u;
        #pragma unroll
        for (int r = 0; r < SREP; ++r) s += ws[HS_OFF + r * HIST_SIZE + i];
        h[i] = s;
    }
    __syncthreads();
    unsigned p = h[t*4] + h[t*4+1] + h[t*4+2] + h[t*4+3];
    ps[t] = p;
    __syncthreads();
    for (int st = 1; st < 1024; st <<= 1) {
        unsigned v = (t + st < 1024) ? ps[t + st] : 0u;
        __syncthreads();
        ps[t] += v;
        __syncthreads();
    }
    unsigned S = (t < 1023) ? ps[t + 1] : 0u;
    for (int j = 3; j >= 0; --j) {
        int b = t * 4 + j;
        unsigned Sb = S + h[b];
        if (Sb >= thr && S < thr) F_sh = ((unsigned)b) << 20;
        S = Sb;
    }
    __syncthreads();
    if (t == 0) ws[META_OFF + 4] = F_sh;
}

__device__ __forceinline__ void cand_elem(float a, unsigned idx, unsigned lo, unsigned hi,
                                          unsigned* lh, unsigned* lcnt, uint2* lc,
                                          unsigned* gcnt, uint2* cand, unsigned cap) {
    float r = a > 0.0f ? a : 0.0f;
    unsigned b = __float_as_uint(r);
    if (b >= lo && b < hi) {
        atomicAdd(&lh[b >> 20], 1u);
        unsigned p = atomicAdd(lcnt, 1u);
        if (p < LCAP) lc[p] = make_uint2(b, idx);
        else { unsigned q = atomicAdd(gcnt, 1u); if (q < cap) cand[q] = make_uint2(b, idx); }
    }
}

// K3 (2048 blocks): single x pass — out=0 dense, hist(>=F), compact cands.
__global__ void k_main(const float4* __restrict__ x, float4* __restrict__ out,
                       unsigned* __restrict__ ws, uint2* __restrict__ cand, unsigned cap) {
    __shared__ unsigned lh[HIST_SIZE];
    __shared__ uint2 lc[LCAP];
    __shared__ unsigned lcnt, gbase;
    for (int i = threadIdx.x; i < HIST_SIZE; i += blockDim.x) lh[i] = 0u;
    if (threadIdx.x == 0) lcnt = 0u;
    __syncthreads();
    unsigned* meta = ws + META_OFF;
    unsigned F = meta[4];
    unsigned* gcnt = &meta[0];
    const float4 z = make_float4(0.f, 0.f, 0.f, 0.f);
    int stride = gridDim.x * blockDim.x;
    for (int i = blockIdx.x * blockDim.x + threadIdx.x; i < NV; i += stride) {
        float4 v = x[i];
        out[i] = z;
        unsigned base = (unsigned)i * 4u;
        cand_elem(v.x, base + 0u, F, 0xFFFFFFFFu, lh, &lcnt, lc, gcnt, cand, cap);
        cand_elem(v.y, base + 1u, F, 0xFFFFFFFFu, lh, &lcnt, lc, gcnt, cand, cap);
        cand_elem(v.z, base + 2u, F, 0xFFFFFFFFu, lh, &lcnt, lc, gcnt, cand, cap);
        cand_elem(v.w, base + 3u, F, 0xFFFFFFFFu, lh, &lcnt, lc, gcnt, cand, cap);
    }
    __syncthreads();
    unsigned* gh = ws + H_OFF + (blockIdx.x & (HREP - 1)) * HIST_SIZE;
    for (int i = threadIdx.x; i < HIST_SIZE; i += blockDim.x)
        if (lh[i]) atomicAdd(&gh[i], lh[i]);
    unsigned n = lcnt < LCAP ? lcnt : LCAP;
    if (threadIdx.x == 0 && n) gbase = atomicAdd(gcnt, n);
    __syncthreads();
    for (unsigned e = threadIdx.x; e < n; e += blockDim.x) {
        unsigned q = gbase + e;
        if (q < cap) cand[q] = lc[e];
    }
}

// K5 (guarded): complement pass (0 < bits < F) restoring full-histogram exactness.
__global__ void k_main_fb(const float4* __restrict__ x, unsigned* __restrict__ ws,
                          uint2* __restrict__ cand, unsigned cap) {
    unsigned* meta = ws + META_OFF;
    if (meta[3] == 0u) return;
    __shared__ unsigned lh[HIST_SIZE];
    __shared__ uint2 lc[LCAP];
    __shared__ unsigned lcnt, gbase;
    for (int i = threadIdx.x; i < HIST_SIZE; i += blockDim.x) lh[i] = 0u;
    if (threadIdx.x == 0) lcnt = 0u;
    __syncthreads();
    unsigned F = meta[4];
    unsigned* gcnt = &meta[0];
    int stride = gridDim.x * blockDim.x;
    for (int i = blockIdx.x * blockDim.x + threadIdx.x; i < NV; i += stride) {
        float4 v = x[i];
        unsigned base = (unsigned)i * 4u;
        cand_elem(v.x, base + 0u, 1u, F, lh, &lcnt, lc, gcnt, cand, cap);
        cand_elem(v.y, base + 1u, 1u, F, lh, &lcnt, lc, gcnt, cand, cap);
        cand_elem(v.z, base + 2u, 1u, F, lh, &lcnt, lc, gcnt, cand, cap);
        cand_elem(v.w, base + 3u, 1u, F, lh, &lcnt, lc, gcnt, cand, cap);
    }
    __syncthreads();
    unsigned* gh = ws + H_OFF + (blockIdx.x & (HREP - 1)) * HIST_SIZE;
    for (int i = threadIdx.x; i < HIST_SIZE; i += blockDim.x)
        if (lh[i]) atomicAdd(&gh[i], lh[i]);
    unsigned n = lcnt < LCAP ? lcnt : LCAP;
    if (threadIdx.x == 0 && n) gbase = atomicAdd(gcnt, n);
    __syncthreads();
    for (unsigned e = threadIdx.x; e < n; e += blockDim.x) {
        unsigned q = gbase + e;
        if (q < cap) cand[q] = lc[e];
    }
}

// K4/K6 (1 block): suffix-scan replica-summed hist -> b12, c_above | fail | keepall.
__global__ void k_scan(unsigned* __restrict__ ws, const int* __restrict__ kptr, int is_fb) {
    unsigned* meta = ws + META_OFF;
    if (is_fb && meta[3] == 0u) return;
    __shared__ unsigned h[HIST_SIZE];
    __shared__ unsigned ps[1024];
    int t = threadIdx.x;
    unsigned nk = (unsigned)(*kptr) * 1024u;
    for (int i = t; i < HIST_SIZE; i += 1024) {
        unsigned s = 0u;
        #pragma unroll
        for (int r = 0; r < HREP; ++r) s += ws[H_OFF + r * HIST_SIZE + i];
        h[i] = s;
    }
    __syncthreads();
    unsigned p = h[t*4] + h[t*4+1] + h[t*4+2] + h[t*4+3];
    ps[t] = p;
    __syncthreads();
    for (int st = 1; st < 1024; st <<= 1) {
        unsigned v = (t + st < 1024) ? ps[t + st] : 0u;
        __syncthreads();
        ps[t] += v;
        __syncthreads();
    }
    unsigned total = ps[0];
    if (total < nk) {
        if (t == 0) { if (!is_fb) meta[3] = 1u; else meta[5] = 1u; }
        return;
    }
    unsigned S = (t < 1023) ? ps[t + 1] : 0u;
    for (int j = 3; j >= 0; --j) {
        int b = t * 4 + j;
        unsigned Sb = S + h[b];
        if (Sb >= nk && S < nk) { meta[1] = (unsigned)b; meta[2] = S; }
        S = Sb;
    }
}

// K7 (256 blocks): extract cutoff-bucket cands -> cand2, level-2 hist replicas.
__global__ void k_filter(unsigned* __restrict__ ws, const uint2* __restrict__ cand,
                         uint2* __restrict__ cand2, unsigned cap) {
    unsigned* meta = ws + META_OFF;
    if (meta[5]) return;
    __shared__ uint2 lc[LCAP2];
    __shared__ unsigned lcnt, gbase;
    if (threadIdx.x == 0) lcnt = 0u;
    __syncthreads();
    unsigned ncand = meta[0]; if (ncand > cap) ncand = cap;
    unsigned b12 = meta[1];
    unsigned* h2 = ws + H2_OFF + (blockIdx.x & (HREP - 1)) * HIST_SIZE;
    unsigned* cnt2 = &meta[7];
    unsigned stride = gridDim.x * blockDim.x;
    for (unsigned i = blockIdx.x * blockDim.x + threadIdx.x; i < ncand; i += stride) {
        uint2 c = cand[i];
        if ((c.x >> 20) == b12) {
            atomicAdd(&h2[(c.x >> 8) & 0xFFFu], 1u);
            unsigned p = atomicAdd(&lcnt, 1u);
            if (p < LCAP2) lc[p] = c;
            else { unsigned q = atomicAdd(cnt2, 1u); if (q < CAND2_CAP) cand2[q] = c; }
        }
    }
    __syncthreads();
    unsigned n = lcnt < LCAP2 ? lcnt : LCAP2;
    if (threadIdx.x == 0 && n) gbase = atomicAdd(cnt2, n);
    __syncthreads();
    for (unsigned e = threadIdx.x; e < n; e += blockDim.x) {
        unsigned q = gbase + e;
        if (q < CAND2_CAP) cand2[q] = lc[e];
    }
}

// K8 (1 block): level-2/3 refinement -> exact tau (meta[6]); write the r
// lowest-index exact-tie keepers directly.
__global__ void k_select(unsigned* __restrict__ ws, const uint2* __restrict__ cand2,
                         float* __restrict__ out, const int* __restrict__ kptr) {
    unsigned* meta = ws + META_OFF;
    if (meta[5]) return;
    __shared__ unsigned h[HIST_SIZE];
    __shared__ unsigned ps[1024];
    __shared__ unsigned h3[256];
    __shared__ int ties[TIE_CAP];
    __shared__ unsigned tie_cnt;
    __shared__ unsigned s2_sh, ca2_sh, t3_sh, ca3_sh;
    int t = threadIdx.x;
    unsigned nk = (unsigned)(*kptr) * 1024u;
    unsigned b12 = meta[1];
    unsigned m = nk - meta[2];                     // rank within bucket b12, >=1
    unsigned n2 = meta[7]; if (n2 > CAND2_CAP) n2 = CAND2_CAP;
    for (int i = t; i < HIST_SIZE; i += 1024) {
        unsigned s = 0u;
        #pragma unroll
        for (int r = 0; r < HREP; ++r) s += ws[H2_OFF + r * HIST_SIZE + i];
        h[i] = s;
    }
    if (t < 256) h3[t] = 0u;
    if (t == 0) tie_cnt = 0u;
    __syncthreads();
    unsigned p = h[t*4] + h[t*4+1] + h[t*4+2] + h[t*4+3];
    ps[t] = p;
    __syncthreads();
    for (int st = 1; st < 1024; st <<= 1) {
        unsigned v = (t + st < 1024) ? ps[t + st] : 0u;
        __syncthreads();
        ps[t] += v;
        __syncthreads();
    }
    {
        unsigned S = (t < 1023) ? ps[t + 1] : 0u;
        for (int j = 3; j >= 0; --j) {
            int b = t * 4 + j;
            unsigned Sb = S + h[b];
            if (Sb >= m && S < m) { s2_sh = (unsigned)b; ca2_sh = S; }
            S = Sb;
        }
    }
    __syncthreads();
    unsigned s2 = s2_sh;
    unsigned m2 = m - ca2_sh;                      // rank within sub-bucket, >=1
    for (unsigned i = t; i < n2; i += 1024) {
        uint2 c = cand2[i];
        if (((c.x >> 8) & 0xFFFu) == s2) atomicAdd(&h3[c.x & 0xFFu], 1u);
    }
    __syncthreads();
    if (t < 256) ps[t] = h3[t];
    __syncthreads();
    for (int st = 1; st < 256; st <<= 1) {
        unsigned v = 0u;
        if (t < 256) v = (t + st < 256) ? ps[t + st] : 0u;
        __syncthreads();
        if (t < 256) ps[t] += v;
        __syncthreads();
    }
    if (t < 256) {
        unsigned S3 = (t < 255) ? ps[t + 1] : 0u;
        unsigned Sb = S3 + h3[t];
        if (Sb >= m2 && S3 < m2) { t3_sh = (unsigned)t; ca3_sh = S3; }
    }
    __syncthreads();
    unsigned tau = (b12 << 20) | (s2 << 8) | t3_sh;
    unsigned r = m2 - ca3_sh;                      // exact-tie keepers
    if (t == 0) meta[6] = tau;
    for (unsigned i = t; i < n2; i += 1024) {
        uint2 c = cand2[i];
        if (c.x == tau) {
            unsigned q = atomicAdd(&tie_cnt, 1u);
            if (q < TIE_CAP) ties[q] = (int)c.y;
        }
    }
    __syncthreads();
    unsigned tc = tie_cnt; if (tc > TIE_CAP) tc = TIE_CAP;
    float tv = __uint_as_float(tau);
    for (unsigned e = t; e < tc; e += 1024) {
        int my = ties[e];
        unsigned rank = 0u;
        for (unsigned j = 0; j < tc; ++j) rank += (ties[j] < my) ? 1u : 0u;
        if (rank < r) out[my] = tv;                // keep r lowest-index ties
    }
}

// K9 (512 blocks): sparse scatter of definite keepers (bits > tau), or all if keepall.
__global__ void k_scatter(const unsigned* __restrict__ ws, const uint2* __restrict__ cand,
                          float* __restrict__ out, unsigned cap) {
    const unsigned* meta = ws + META_OFF;
    unsigned keepall = meta[5];
    unsigned tau = meta[6];
    unsigned ncand = meta[0]; if (ncand > cap) ncand = cap;
    unsigned stride = gridDim.x * blockDim.x;
    for (unsigned i = blockIdx.x * blockDim.x + threadIdx.x; i < ncand; i += stride) {
        uint2 c = cand[i];
        if (keepall || c.x > tau) out[c.y] = __uint_as_float(c.x);
    }
}

extern "C" void kernel_launch(void* const* d_in, const int* in_sizes, int n_in,
                              void* d_out, int out_size, void* d_ws, size_t ws_size,
                              hipStream_t stream) {
    const float4* x = (const float4*)d_in[0];
    const int* kptr = (const int*)d_in[1];
    float* out = (float*)d_out;
    unsigned* ws32 = (unsigned*)d_ws;
    uint2* cand2 = (uint2*)(ws32 + CAND2_OFF);
    uint2* cand  = (uint2*)(ws32 + CAND_OFF);

    unsigned cap = CAND_CAP;
    size_t hdr = (size_t)CAND_OFF * 4;
    if (ws_size < hdr + (size_t)CAND_CAP * 8) {
        cap = (ws_size > hdr) ? (unsigned)((ws_size - hdr) / 8) : 0u;
    }

    k_sample<<<SREP, 256, 0, stream>>>(x, ws32);
    k_pick<<<1, 1024, 0, stream>>>(ws32, kptr);
    k_main<<<2048, 256, 0, stream>>>(x, (float4*)out, ws32, cand, cap);
    k_scan<<<1, 1024, 0, stream>>>(ws32, kptr, 0);
    k_main_fb<<<2048, 256, 0, stream>>>(x, ws32, cand, cap);    // no-op unless fail
    k_scan<<<1, 1024, 0, stream>>>(ws32, kptr, 1);              // no-op unless fail
    k_filter<<<256, 256, 0, stream>>>(ws32, cand, cand2, cap);
    k_select<<<1, 1024, 0, stream>>>(ws32, cand2, out, kptr);
    k_scatter<<<512, 256, 0, stream>>>(ws32, cand, out, cap);
}